// Round 6
// baseline (150.890 us; speedup 1.0000x reference)
//
#include <hip/hip_runtime.h>
#include <math.h>

#define NN 5000      // nodes
#define GG 16        // graphs (B*D)
#define VV 256       // vocab
#define FF 64        // in channels
#define HH 4         // heads
#define CC 32        // channels/head
#define HC 128       // H*C
#define EE 80000     // edges before self loops
#define NEG 0.2f
#define SLOT 48      // edge chunk per node per pass
#define SPAD 50      // padded slot stride
#define CAP 96       // bucket capacity per node (1 + max in-degree ~46 for this E/N)
#define NTASK (GG * NN / 4)   // 20000 wave-tasks (4 instances each)
#define TW 16        // waves per k_gat block
#define GRIDB 512    // 256 task-groups x 2 channel-halves
#define TSTRIDE ((GRIDB / 2) * TW)   // 4096 task-slots per half

// ---------------------------------------------------------------------------
// Kernel 1 (R5-proven, verbatim): blocks 0..VV-1 build T row v + as_t/ad_t;
// tail blocks init bucket: cursor[n]=1, self-loop in slot 0.
// ---------------------------------------------------------------------------
__global__ void k_tables(const float* __restrict__ emb, const float* __restrict__ W,
                         const float* __restrict__ att_src, const float* __restrict__ att_dst,
                         float* __restrict__ T, float* __restrict__ as_t, float* __restrict__ ad_t,
                         int* __restrict__ cursor, int* __restrict__ csr) {
  if (blockIdx.x >= VV) {
    int n = (blockIdx.x - VV) * 128 + threadIdx.x;
    if (n < NN) {
      cursor[n] = 1;        // slot 0 taken by self loop
      csr[n * CAP] = n;     // self-loop entry
    }
    return;
  }
  __shared__ float se[FF];
  __shared__ float sT[HC];
  const int v = blockIdx.x;
  const int k = threadIdx.x;          // 0..127
  if (k < FF) se[k] = emb[v * FF + k];
  __syncthreads();
  float acc = 0.f;
#pragma unroll
  for (int f = 0; f < FF; ++f) acc += se[f] * W[f * HC + k];
  T[v * HC + k] = acc;
  sT[k] = acc;
  __syncthreads();
  if (k < 2 * HH) {
    const int h = k >> 1;
    const float* att = (k & 1) ? att_dst : att_src;
    float s = 0.f;
#pragma unroll
    for (int c = 0; c < CC; ++c) s += sT[h * CC + c] * att[h * CC + c];
    if (k & 1) ad_t[v * HH + h] = s;
    else       as_t[v * HH + h] = s;
  }
}

// ---------------------------------------------------------------------------
// Kernel 2 (R5-proven, verbatim): scatter into fixed-capacity buckets +
// P table. P[d*VV+v] (float4 over heads) = exp(leaky_relu(as[v] + ad[d]))
// ---------------------------------------------------------------------------
#define NSCAT ((EE + 255) / 256)
__global__ void k_scatter_p(const int* __restrict__ src, const int* __restrict__ dst,
                            int* __restrict__ cursor, int* __restrict__ csr,
                            const float* __restrict__ as_t, const float* __restrict__ ad_t,
                            float* __restrict__ P) {
  if (blockIdx.x < NSCAT) {
    int e = blockIdx.x * 256 + threadIdx.x;
    if (e < EE) {
      int d = dst[e];
      int pos = atomicAdd(&cursor[d], 1);
      if (pos < CAP) csr[d * CAP + pos] = src[e];
    }
    return;
  }
  const int d = blockIdx.x - NSCAT;   // 0..255
  const int v = threadIdx.x;          // 0..255
  const float4 a = ((const float4*)as_t)[v];
  const float4 b = ((const float4*)ad_t)[d];
  float e0 = a.x + b.x; e0 = e0 > 0.f ? e0 : NEG * e0;
  float e1 = a.y + b.y; e1 = e1 > 0.f ? e1 : NEG * e1;
  float e2 = a.z + b.z; e2 = e2 > 0.f ? e2 : NEG * e2;
  float e3 = a.w + b.w; e3 = e3 > 0.f ? e3 : NEG * e3;
  float4 p;
  p.x = __expf(e0); p.y = __expf(e1); p.z = __expf(e2); p.w = __expf(e3);
  ((float4*)P)[d * VV + v] = p;
}

// ---------------------------------------------------------------------------
// Main kernel: T-half staged in LDS; 16 waves/block grid-stride over the
// proven 4-instance wave-tasks. Channel phase reads T from LDS (was L2).
// blockIdx&1 selects the channel half (0: ch 0..63, 1: ch 64..127).
// ---------------------------------------------------------------------------
__global__ __launch_bounds__(1024)
void k_gat(const int* __restrict__ x, const int* __restrict__ cursor,
           const int* __restrict__ csr, const float* __restrict__ T,
           const float* __restrict__ P, const float* __restrict__ bias,
           float* __restrict__ out) {
  __shared__ float  sT[VV * 64];          // 64 KB: one channel-half of T
  __shared__ float4 s_p4[TW][4][SPAD];    // 51200 B
  __shared__ int    s_ofs[TW][4][SPAD];   // 12800 B   -> total 126.5 KiB

  const int tid = threadIdx.x;
  const int hf  = blockIdx.x & 1;

  // stage T half: columns [hf*64, hf*64+64) of T[256][128]
  {
    const float4* __restrict__ Tg4 = (const float4*)T;   // [VV][32]
    float4* sT4 = (float4*)sT;
    for (int i = tid; i < VV * 16; i += 1024) {
      const int v = i >> 4, c4 = i & 15;
      sT4[i] = Tg4[v * 32 + hf * 16 + c4];
    }
  }
  __syncthreads();

  const int wave = tid >> 6;
  const int lane = tid & 63;
  const int sub  = lane >> 4;             // which of 4 instances
  const int sl   = lane & 15;             // sub-lane within instance group
  const int head = hf * 2 + (sl >> 3);    // my 4 channels live in this head

  const float4 b0 = ((const float4*)bias)[hf * 16 + sl];

  for (int t = (blockIdx.x >> 1) * TW + wave; t < NTASK; t += TSTRIDE) {
    const int inst = t * 4 + sub;             // g*NN + n (NN%4==0: no crossing)
    const int g    = inst / NN;
    const int n    = inst - g * NN;

    const int base = n * CAP;
    const int deg  = min(cursor[n], CAP);     // includes self loop (slot 0)
    const int xd   = x[inst];
    const float4* __restrict__ Pd = ((const float4*)P) + xd * VV;
    const int* __restrict__ xg = x + g * NN;

    float4 dsum = make_float4(0.f, 0.f, 0.f, 0.f);
    float4 a0 = make_float4(0.f, 0.f, 0.f, 0.f);

    for (int c0 = 0; c0 < deg; c0 += SLOT) {
      const int len = min(SLOT, deg - c0);
      // gather phase (proven): 16 sub-lanes stride over this node's edges
      for (int r = sl; r < len; r += 16) {
        const int srcn = csr[base + c0 + r];
        const int xv   = xg[srcn];
        const float4 p4 = Pd[xv];
        dsum.x += p4.x; dsum.y += p4.y; dsum.z += p4.z; dsum.w += p4.w;
        s_p4[wave][sub][r]  = p4;
        s_ofs[wave][sub][r] = xv << 6;   // xv*64 element offset into sT
      }
      __threadfence_block();   // drain LDS writes before cross-lane reads
      // channel phase: each lane accumulates its 4 channels from LDS T
#pragma unroll 4
      for (int j = 0; j < len; ++j) {
        const int   ofs = s_ofs[wave][sub][j];
        const float p   = ((const float*)&s_p4[wave][sub][j])[head];
        const float4 t0 = *(const float4*)&sT[ofs + sl * 4];
        a0.x += p * t0.x; a0.y += p * t0.y; a0.z += p * t0.z; a0.w += p * t0.w;
      }
      __threadfence_block();   // WAR guard before buffers are overwritten
    }

    // denominator: butterfly over the 16-lane group
#pragma unroll
    for (int d = 1; d < 16; d <<= 1) {
      dsum.x += __shfl_xor(dsum.x, d);
      dsum.y += __shfl_xor(dsum.y, d);
      dsum.z += __shfl_xor(dsum.z, d);
      dsum.w += __shfl_xor(dsum.w, d);
    }
    const float den = hf ? ((sl & 8) ? dsum.w : dsum.z)
                         : ((sl & 8) ? dsum.y : dsum.x);
    const float r = 1.f / den;

    float4 o;
    o.x = a0.x * r + b0.x; o.y = a0.y * r + b0.y;
    o.z = a0.z * r + b0.z; o.w = a0.w * r + b0.w;
    *(float4*)&out[(size_t)inst * HC + hf * 64 + sl * 4] = o;
  }
}

// ---------------------------------------------------------------------------
extern "C" void kernel_launch(void* const* d_in, const int* in_sizes, int n_in,
                              void* d_out, int out_size, void* d_ws, size_t ws_size,
                              hipStream_t stream) {
  const int*   x       = (const int*)d_in[0];      // [G,N]
  const int*   adj     = (const int*)d_in[1];      // [2,E]
  const float* emb     = (const float*)d_in[2];    // [V,F]
  const float* W       = (const float*)d_in[3];    // [F,HC]
  const float* att_src = (const float*)d_in[4];    // [H,C]
  const float* att_dst = (const float*)d_in[5];    // [H,C]
  const float* bias    = (const float*)d_in[6];    // [HC]
  float*       out     = (float*)d_out;

  const int* adj_src = adj;
  const int* adj_dst = adj + EE;

  // workspace carve-up (region sizes multiples of 16 B)
  char* wp = (char*)d_ws;
  float* T    = (float*)wp; wp += (size_t)VV * HC * 4;       // 128 KB
  float* as_t = (float*)wp; wp += (size_t)VV * HH * 4;       // 4 KB
  float* ad_t = (float*)wp; wp += (size_t)VV * HH * 4;       // 4 KB
  int* cursor = (int*)wp;   wp += (size_t)NN * 4;            // 20000 B
  int* csr    = (int*)wp;   wp += (size_t)NN * CAP * 4;      // 1.92 MB
  float* P    = (float*)wp; wp += (size_t)VV * VV * HH * 4;  // 1 MB

  const int initblk = (NN + 127) / 128;                      // 40
  k_tables<<<VV + initblk, 128, 0, stream>>>(emb, W, att_src, att_dst,
                                             T, as_t, ad_t, cursor, csr);
  k_scatter_p<<<NSCAT + VV, 256, 0, stream>>>(adj_src, adj_dst, cursor, csr,
                                              as_t, ad_t, P);
  k_gat<<<GRIDB, 1024, 0, stream>>>(x, cursor, csr, T, P, bias, out);
}

// Round 7
// 139.852 us; speedup vs baseline: 1.0789x; 1.0789x over previous
//
#include <hip/hip_runtime.h>
#include <math.h>

#define NN 5000      // nodes
#define GG 16        // graphs (B*D)
#define VV 256       // vocab
#define FF 64        // in channels
#define HH 4         // heads
#define CC 32        // channels/head
#define HC 128       // H*C
#define EE 80000     // edges before self loops
#define NEG 0.2f
#define SLOT 16      // edge chunk per node per pass (deg~17 -> 1-2 chunks)
#define SPAD 18      // padded slot stride: 18*5 dwords/slot-entry decorrelates banks
#define CAP 96       // bucket capacity per node (1 + max in-degree ~46 for this E/N)
#define NTASK (GG * NN / 4)   // 20000 wave-tasks (4 instances each)
#define TW 16        // waves per k_gat block
#define GATB 256     // one block per CU
#define TSTRIDE (GATB * TW)   // 4096 wave-slots
#define TSTR 132     // LDS T row stride in dwords (132 % 32 = 4 -> row comb rotation)

// ---------------------------------------------------------------------------
// Kernel 1 (R5-proven, verbatim): blocks 0..VV-1 build T row v + as_t/ad_t;
// tail blocks init bucket: cursor[n]=1, self-loop in slot 0.
// ---------------------------------------------------------------------------
__global__ void k_tables(const float* __restrict__ emb, const float* __restrict__ W,
                         const float* __restrict__ att_src, const float* __restrict__ att_dst,
                         float* __restrict__ T, float* __restrict__ as_t, float* __restrict__ ad_t,
                         int* __restrict__ cursor, int* __restrict__ csr) {
  if (blockIdx.x >= VV) {
    int n = (blockIdx.x - VV) * 128 + threadIdx.x;
    if (n < NN) {
      cursor[n] = 1;        // slot 0 taken by self loop
      csr[n * CAP] = n;     // self-loop entry
    }
    return;
  }
  __shared__ float se[FF];
  __shared__ float sT[HC];
  const int v = blockIdx.x;
  const int k = threadIdx.x;          // 0..127
  if (k < FF) se[k] = emb[v * FF + k];
  __syncthreads();
  float acc = 0.f;
#pragma unroll
  for (int f = 0; f < FF; ++f) acc += se[f] * W[f * HC + k];
  T[v * HC + k] = acc;
  sT[k] = acc;
  __syncthreads();
  if (k < 2 * HH) {
    const int h = k >> 1;
    const float* att = (k & 1) ? att_dst : att_src;
    float s = 0.f;
#pragma unroll
    for (int c = 0; c < CC; ++c) s += sT[h * CC + c] * att[h * CC + c];
    if (k & 1) ad_t[v * HH + h] = s;
    else       as_t[v * HH + h] = s;
  }
}

// ---------------------------------------------------------------------------
// Kernel 2 (R5-proven, verbatim): scatter into fixed-capacity buckets +
// P table. P[d*VV+v] (float4 over heads) = exp(leaky_relu(as[v] + ad[d]))
// ---------------------------------------------------------------------------
#define NSCAT ((EE + 255) / 256)
__global__ void k_scatter_p(const int* __restrict__ src, const int* __restrict__ dst,
                            int* __restrict__ cursor, int* __restrict__ csr,
                            const float* __restrict__ as_t, const float* __restrict__ ad_t,
                            float* __restrict__ P) {
  if (blockIdx.x < NSCAT) {
    int e = blockIdx.x * 256 + threadIdx.x;
    if (e < EE) {
      int d = dst[e];
      int pos = atomicAdd(&cursor[d], 1);
      if (pos < CAP) csr[d * CAP + pos] = src[e];
    }
    return;
  }
  const int d = blockIdx.x - NSCAT;   // 0..255
  const int v = threadIdx.x;          // 0..255
  const float4 a = ((const float4*)as_t)[v];
  const float4 b = ((const float4*)ad_t)[d];
  float e0 = a.x + b.x; e0 = e0 > 0.f ? e0 : NEG * e0;
  float e1 = a.y + b.y; e1 = e1 > 0.f ? e1 : NEG * e1;
  float e2 = a.z + b.z; e2 = e2 > 0.f ? e2 : NEG * e2;
  float e3 = a.w + b.w; e3 = e3 > 0.f ? e3 : NEG * e3;
  float4 p;
  p.x = __expf(e0); p.y = __expf(e1); p.z = __expf(e2); p.w = __expf(e3);
  ((float4*)P)[d * VV + v] = p;
}

// ---------------------------------------------------------------------------
// Main kernel: FULL fp32 T staged in LDS (row stride 132 dwords), 16 waves
// per block, one block per CU, waves grid-stride over the proven 4-instance
// tasks. Channel phase: lane sl covers channels {sl*4..+3} and {64+sl*4..+3}
// (bank-tiling layout), reads T from LDS instead of L2.
// ---------------------------------------------------------------------------
__global__ __launch_bounds__(1024, 1)
void k_gat(const int* __restrict__ x, const int* __restrict__ cursor,
           const int* __restrict__ csr, const float* __restrict__ T,
           const float* __restrict__ P, const float* __restrict__ bias,
           float* __restrict__ out) {
  __shared__ float  sT[VV * TSTR];          // 135168 B
  __shared__ float4 s_p4[TW][4][SPAD];      //  18432 B
  __shared__ int    s_ofs[TW][4][SPAD];     //   4608 B   -> 158208 B total

  const int tid = threadIdx.x;

  // stage full T: sT[v*132 + c] = T[v*128 + c]   (float4 granularity)
  {
    const float4* __restrict__ Tg4 = (const float4*)T;   // [VV][32]
    float4* sT4 = (float4*)sT;                           // row stride 33
    for (int i = tid; i < VV * 32; i += 1024) {
      const int v = i >> 5, c4 = i & 31;
      sT4[v * 33 + c4] = Tg4[i];
    }
  }
  __syncthreads();

  const int wave = tid >> 6;
  const int lane = tid & 63;
  const int sub  = lane >> 4;             // which of 4 instances
  const int sl   = lane & 15;             // sub-lane within instance group
  const int sl4  = sl * 4;
  const int hsel = sl >> 3;               // 0: heads {0,2}, 1: heads {1,3}

  const float4 b_lo = ((const float4*)bias)[sl];        // ch sl*4
  const float4 b_hi = ((const float4*)bias)[16 + sl];   // ch 64+sl*4

  for (int t = blockIdx.x * TW + wave; t < NTASK; t += TSTRIDE) {
    const int inst = t * 4 + sub;             // g*NN + n (NN%4==0: no crossing)
    const int g    = inst / NN;
    const int n    = inst - g * NN;

    const int base = n * CAP;
    const int deg  = min(cursor[n], CAP);     // includes self loop (slot 0)
    const int xd   = x[inst];
    const float4* __restrict__ Pd = ((const float4*)P) + xd * VV;
    const int* __restrict__ xg = x + g * NN;

    float4 dsum = make_float4(0.f, 0.f, 0.f, 0.f);
    float4 a_lo = make_float4(0.f, 0.f, 0.f, 0.f);
    float4 a_hi = make_float4(0.f, 0.f, 0.f, 0.f);

    for (int c0 = 0; c0 < deg; c0 += SLOT) {
      const int len = min(SLOT, deg - c0);
      // gather phase (R5-proven): 16 sub-lanes stride over this node's edges
      for (int r = sl; r < len; r += 16) {
        const int srcn = csr[base + c0 + r];
        const int xv   = xg[srcn];
        const float4 p4 = Pd[xv];
        dsum.x += p4.x; dsum.y += p4.y; dsum.z += p4.z; dsum.w += p4.w;
        s_p4[wave][sub][r]  = p4;
        s_ofs[wave][sub][r] = xv * TSTR;   // LDS row base (dwords)
      }
      __threadfence_block();   // drain LDS writes before cross-lane reads
      // channel phase: each lane accumulates 8 channels from LDS T
#pragma unroll 4
      for (int j = 0; j < len; ++j) {
        const int    ofs = s_ofs[wave][sub][j];
        const float* pp  = (const float*)&s_p4[wave][sub][j];
        const float  plo = pp[hsel];           // head 0 or 1
        const float  phi = pp[2 + hsel];       // head 2 or 3
        const float4 t0 = *(const float4*)&sT[ofs + sl4];
        const float4 t1 = *(const float4*)&sT[ofs + 64 + sl4];
        a_lo.x += plo * t0.x; a_lo.y += plo * t0.y;
        a_lo.z += plo * t0.z; a_lo.w += plo * t0.w;
        a_hi.x += phi * t1.x; a_hi.y += phi * t1.y;
        a_hi.z += phi * t1.z; a_hi.w += phi * t1.w;
      }
      __threadfence_block();   // WAR guard before buffers are overwritten
    }

    // denominator: butterfly over the 16-lane group
#pragma unroll
    for (int d = 1; d < 16; d <<= 1) {
      dsum.x += __shfl_xor(dsum.x, d);
      dsum.y += __shfl_xor(dsum.y, d);
      dsum.z += __shfl_xor(dsum.z, d);
      dsum.w += __shfl_xor(dsum.w, d);
    }
    const float den_lo = hsel ? dsum.y : dsum.x;
    const float den_hi = hsel ? dsum.w : dsum.z;
    const float r_lo = 1.f / den_lo;
    const float r_hi = 1.f / den_hi;

    float4 o0, o1;
    o0.x = a_lo.x * r_lo + b_lo.x; o0.y = a_lo.y * r_lo + b_lo.y;
    o0.z = a_lo.z * r_lo + b_lo.z; o0.w = a_lo.w * r_lo + b_lo.w;
    o1.x = a_hi.x * r_hi + b_hi.x; o1.y = a_hi.y * r_hi + b_hi.y;
    o1.z = a_hi.z * r_hi + b_hi.z; o1.w = a_hi.w * r_hi + b_hi.w;
    float* op = out + (size_t)inst * HC;
    *(float4*)(op + sl4) = o0;
    *(float4*)(op + 64 + sl4) = o1;
  }
}

// ---------------------------------------------------------------------------
extern "C" void kernel_launch(void* const* d_in, const int* in_sizes, int n_in,
                              void* d_out, int out_size, void* d_ws, size_t ws_size,
                              hipStream_t stream) {
  const int*   x       = (const int*)d_in[0];      // [G,N]
  const int*   adj     = (const int*)d_in[1];      // [2,E]
  const float* emb     = (const float*)d_in[2];    // [V,F]
  const float* W       = (const float*)d_in[3];    // [F,HC]
  const float* att_src = (const float*)d_in[4];    // [H,C]
  const float* att_dst = (const float*)d_in[5];    // [H,C]
  const float* bias    = (const float*)d_in[6];    // [HC]
  float*       out     = (float*)d_out;

  const int* adj_src = adj;
  const int* adj_dst = adj + EE;

  // workspace carve-up (region sizes multiples of 16 B)
  char* wp = (char*)d_ws;
  float* T    = (float*)wp; wp += (size_t)VV * HC * 4;       // 128 KB
  float* as_t = (float*)wp; wp += (size_t)VV * HH * 4;       // 4 KB
  float* ad_t = (float*)wp; wp += (size_t)VV * HH * 4;       // 4 KB
  int* cursor = (int*)wp;   wp += (size_t)NN * 4;            // 20000 B
  int* csr    = (int*)wp;   wp += (size_t)NN * CAP * 4;      // 1.92 MB
  float* P    = (float*)wp; wp += (size_t)VV * VV * HH * 4;  // 1 MB

  const int initblk = (NN + 127) / 128;                      // 40
  k_tables<<<VV + initblk, 128, 0, stream>>>(emb, W, att_src, att_dst,
                                             T, as_t, ad_t, cursor, csr);
  k_scatter_p<<<NSCAT + VV, 256, 0, stream>>>(adj_src, adj_dst, cursor, csr,
                                              as_t, ad_t, P);
  k_gat<<<GATB, 1024, 0, stream>>>(x, cursor, csr, T, P, bias, out);
}

// Round 8
// 135.323 us; speedup vs baseline: 1.1150x; 1.0335x over previous
//
#include <hip/hip_runtime.h>
#include <hip/hip_fp16.h>
#include <math.h>

#define NN 5000      // nodes
#define GG 16        // graphs (B*D)
#define VV 256       // vocab
#define FF 64        // in channels
#define HH 4         // heads
#define CC 32        // channels/head
#define HC 128       // H*C
#define EE 80000     // edges before self loops
#define NEG 0.2f
#define CAP 96       // bucket capacity per node (1 + max in-degree ~46 for this E/N)

// ---------------------------------------------------------------------------
// Kernel 1 (R5-proven + fp16 T write): blocks 0..VV-1 build T16 row v and
// as_t[v], ad_t[v]; tail blocks init bucket: cursor[n]=1, self-loop slot 0.
// ---------------------------------------------------------------------------
__global__ void k_tables(const float* __restrict__ emb, const float* __restrict__ W,
                         const float* __restrict__ att_src, const float* __restrict__ att_dst,
                         __half* __restrict__ T16, float* __restrict__ as_t,
                         float* __restrict__ ad_t,
                         int* __restrict__ cursor, int* __restrict__ csr) {
  if (blockIdx.x >= VV) {
    int n = (blockIdx.x - VV) * 128 + threadIdx.x;
    if (n < NN) {
      cursor[n] = 1;        // slot 0 taken by self loop
      csr[n * CAP] = n;     // self-loop entry
    }
    return;
  }
  __shared__ float se[FF];
  __shared__ float sT[HC];
  const int v = blockIdx.x;
  const int k = threadIdx.x;          // 0..127
  if (k < FF) se[k] = emb[v * FF + k];
  __syncthreads();
  float acc = 0.f;
#pragma unroll
  for (int f = 0; f < FF; ++f) acc += se[f] * W[f * HC + k];
  T16[v * HC + k] = __float2half(acc);
  sT[k] = acc;
  __syncthreads();
  if (k < 2 * HH) {
    const int h = k >> 1;
    const float* att = (k & 1) ? att_dst : att_src;
    float s = 0.f;
#pragma unroll
    for (int c = 0; c < CC; ++c) s += sT[h * CC + c] * att[h * CC + c];
    if (k & 1) ad_t[v * HH + h] = s;
    else       as_t[v * HH + h] = s;
  }
}

// ---------------------------------------------------------------------------
// Kernel 2 (R5-proven, verbatim): scatter into fixed-capacity buckets +
// P table. P[d*VV+v] (float4 over heads) = exp(leaky_relu(as[v] + ad[d]))
// ---------------------------------------------------------------------------
#define NSCAT ((EE + 255) / 256)
__global__ void k_scatter_p(const int* __restrict__ src, const int* __restrict__ dst,
                            int* __restrict__ cursor, int* __restrict__ csr,
                            const float* __restrict__ as_t, const float* __restrict__ ad_t,
                            float* __restrict__ P) {
  if (blockIdx.x < NSCAT) {
    int e = blockIdx.x * 256 + threadIdx.x;
    if (e < EE) {
      int d = dst[e];
      int pos = atomicAdd(&cursor[d], 1);
      if (pos < CAP) csr[d * CAP + pos] = src[e];
    }
    return;
  }
  const int d = blockIdx.x - NSCAT;   // 0..255
  const int v = threadIdx.x;          // 0..255
  const float4 a = ((const float4*)as_t)[v];
  const float4 b = ((const float4*)ad_t)[d];
  float e0 = a.x + b.x; e0 = e0 > 0.f ? e0 : NEG * e0;
  float e1 = a.y + b.y; e1 = e1 > 0.f ? e1 : NEG * e1;
  float e2 = a.z + b.z; e2 = e2 > 0.f ? e2 : NEG * e2;
  float e3 = a.w + b.w; e3 = e3 > 0.f ? e3 : NEG * e3;
  float4 p;
  p.x = __expf(e0); p.y = __expf(e1); p.z = __expf(e2); p.w = __expf(e3);
  ((float4*)P)[d * VV + v] = p;
}

// ---------------------------------------------------------------------------
// Main kernel: one wave = (node n, graph pair gp). 32 lanes per graph,
// lane owns 4 channels. Edge loop is wave-uniform: csr/x reads broadcast,
// T16 row reads are coalesced 256 B segments, P weight broadcasts to its
// 8-lane head group. No LDS, no fences, no shuffles; denominator
// accumulates per-lane (each lane sums its own head's p over all edges).
// ---------------------------------------------------------------------------
__global__ __launch_bounds__(256)
void k_gat(const int* __restrict__ x, const int* __restrict__ cursor,
           const int* __restrict__ csr, const __half* __restrict__ T16,
           const float* __restrict__ P, const float* __restrict__ bias,
           float* __restrict__ out) {
  const int tid  = threadIdx.x;
  const int wave = tid >> 6;
  const int lane = tid & 63;
  const int t    = blockIdx.x * 4 + wave;     // 0 .. NN*8-1 (grid exact)
  const int n    = t >> 3;                    // node
  const int gp   = t & 7;                     // graph pair
  const int g    = gp * 2 + (lane >> 5);      // this half-wave's graph
  const int cl   = lane & 31;                 // channel-lane within graph
  const int c4   = cl * 4;                    // my 4 channels
  const int head = cl >> 3;                   // my channels' head

  const int base = n * CAP;
  const int deg  = min(cursor[n], CAP);       // includes self loop (slot 0)
  const int* __restrict__ xg = x + g * NN;
  const int xd   = xg[n];
  const float* __restrict__ Pg = P + ((size_t)xd << 10) + head;  // [v*4] stride

  float4 acc = make_float4(0.f, 0.f, 0.f, 0.f);
  float dsum = 0.f;

#pragma unroll 2
  for (int j = 0; j < deg; ++j) {
    const int srcn = csr[base + j];           // wave-uniform -> broadcast
    const int xv   = xg[srcn];                // broadcast within 32 lanes
    const float p  = Pg[(size_t)xv << 2];     // broadcast within 8-lane head group
    union { uint2 u; __half2 h2[2]; } tt;
    tt.u = *(const uint2*)&T16[((size_t)xv << 7) + c4];   // coalesced 256 B/graph
    const float2 lo = __half22float2(tt.h2[0]);
    const float2 hi = __half22float2(tt.h2[1]);
    acc.x += p * lo.x; acc.y += p * lo.y;
    acc.z += p * hi.x; acc.w += p * hi.y;
    dsum += p;
  }

  const float r = 1.f / dsum;
  const float4 b4 = ((const float4*)bias)[cl];
  float4 o;
  o.x = acc.x * r + b4.x; o.y = acc.y * r + b4.y;
  o.z = acc.z * r + b4.z; o.w = acc.w * r + b4.w;
  *(float4*)&out[((size_t)(g * NN + n)) * HC + c4] = o;
}

// ---------------------------------------------------------------------------
extern "C" void kernel_launch(void* const* d_in, const int* in_sizes, int n_in,
                              void* d_out, int out_size, void* d_ws, size_t ws_size,
                              hipStream_t stream) {
  const int*   x       = (const int*)d_in[0];      // [G,N]
  const int*   adj     = (const int*)d_in[1];      // [2,E]
  const float* emb     = (const float*)d_in[2];    // [V,F]
  const float* W       = (const float*)d_in[3];    // [F,HC]
  const float* att_src = (const float*)d_in[4];    // [H,C]
  const float* att_dst = (const float*)d_in[5];    // [H,C]
  const float* bias    = (const float*)d_in[6];    // [HC]
  float*       out     = (float*)d_out;

  const int* adj_src = adj;
  const int* adj_dst = adj + EE;

  // workspace carve-up (region sizes multiples of 16 B)
  char* wp = (char*)d_ws;
  __half* T16 = (__half*)wp; wp += (size_t)VV * HC * 2;      // 64 KB
  float* as_t = (float*)wp;  wp += (size_t)VV * HH * 4;      // 4 KB
  float* ad_t = (float*)wp;  wp += (size_t)VV * HH * 4;      // 4 KB
  int* cursor = (int*)wp;    wp += (size_t)NN * 4;           // 20000 B
  int* csr    = (int*)wp;    wp += (size_t)NN * CAP * 4;     // 1.92 MB
  float* P    = (float*)wp;  wp += (size_t)VV * VV * HH * 4; // 1 MB

  const int initblk = (NN + 127) / 128;                      // 40
  k_tables<<<VV + initblk, 128, 0, stream>>>(emb, W, att_src, att_dst,
                                             T16, as_t, ad_t, cursor, csr);
  k_scatter_p<<<NSCAT + VV, 256, 0, stream>>>(adj_src, adj_dst, cursor, csr,
                                              as_t, ad_t, P);
  k_gat<<<NN * 8 / 4, 256, 0, stream>>>(x, cursor, csr, T16, P, bias, out);
}

// Round 9
// 117.084 us; speedup vs baseline: 1.2887x; 1.1558x over previous
//
#include <hip/hip_runtime.h>
#include <hip/hip_fp16.h>
#include <math.h>

#define NN 5000      // nodes
#define GG 16        // graphs (B*D)
#define VV 256       // vocab
#define FF 64        // in channels
#define HH 4         // heads
#define CC 32        // channels/head
#define HC 128       // H*C
#define EE 80000     // edges before self loops
#define NEG 0.2f
#define CAP 96       // bucket capacity per node (1 + max in-degree ~46 for this E/N)

// ---------------------------------------------------------------------------
// Kernel 1 (R8-proven, verbatim): blocks 0..VV-1 build T16 row v and
// as_t[v], ad_t[v]; tail blocks init bucket: cursor[n]=1, self-loop slot 0.
// ---------------------------------------------------------------------------
__global__ void k_tables(const float* __restrict__ emb, const float* __restrict__ W,
                         const float* __restrict__ att_src, const float* __restrict__ att_dst,
                         __half* __restrict__ T16, float* __restrict__ as_t,
                         float* __restrict__ ad_t,
                         int* __restrict__ cursor, int* __restrict__ csr) {
  if (blockIdx.x >= VV) {
    int n = (blockIdx.x - VV) * 128 + threadIdx.x;
    if (n < NN) {
      cursor[n] = 1;        // slot 0 taken by self loop
      csr[n * CAP] = n;     // self-loop entry
    }
    return;
  }
  __shared__ float se[FF];
  __shared__ float sT[HC];
  const int v = blockIdx.x;
  const int k = threadIdx.x;          // 0..127
  if (k < FF) se[k] = emb[v * FF + k];
  __syncthreads();
  float acc = 0.f;
#pragma unroll
  for (int f = 0; f < FF; ++f) acc += se[f] * W[f * HC + k];
  T16[v * HC + k] = __float2half(acc);
  sT[k] = acc;
  __syncthreads();
  if (k < 2 * HH) {
    const int h = k >> 1;
    const float* att = (k & 1) ? att_dst : att_src;
    float s = 0.f;
#pragma unroll
    for (int c = 0; c < CC; ++c) s += sT[h * CC + c] * att[h * CC + c];
    if (k & 1) ad_t[v * HH + h] = s;
    else       as_t[v * HH + h] = s;
  }
}

// ---------------------------------------------------------------------------
// Kernel 2: scatter into buckets (blocks 0..NSCAT-1, R5-proven) +
// P table (blocks NSCAT..NSCAT+VV-1, R5-proven) +
// x-transpose xT[n][g] = x[g][n] (blocks NSCAT+VV.., independent of both).
// ---------------------------------------------------------------------------
#define NSCAT ((EE + 255) / 256)
#define NXT   ((GG * NN + 255) / 256)
__global__ void k_scatter_p(const int* __restrict__ src, const int* __restrict__ dst,
                            int* __restrict__ cursor, int* __restrict__ csr,
                            const float* __restrict__ as_t, const float* __restrict__ ad_t,
                            float* __restrict__ P,
                            const int* __restrict__ x, int* __restrict__ xT) {
  if (blockIdx.x < NSCAT) {
    int e = blockIdx.x * 256 + threadIdx.x;
    if (e < EE) {
      int d = dst[e];
      int pos = atomicAdd(&cursor[d], 1);
      if (pos < CAP) csr[d * CAP + pos] = src[e];
    }
    return;
  }
  if (blockIdx.x < NSCAT + VV) {
    const int d = blockIdx.x - NSCAT;   // 0..255
    const int v = threadIdx.x;          // 0..255
    const float4 a = ((const float4*)as_t)[v];
    const float4 b = ((const float4*)ad_t)[d];
    float e0 = a.x + b.x; e0 = e0 > 0.f ? e0 : NEG * e0;
    float e1 = a.y + b.y; e1 = e1 > 0.f ? e1 : NEG * e1;
    float e2 = a.z + b.z; e2 = e2 > 0.f ? e2 : NEG * e2;
    float e3 = a.w + b.w; e3 = e3 > 0.f ? e3 : NEG * e3;
    float4 p;
    p.x = __expf(e0); p.y = __expf(e1); p.z = __expf(e2); p.w = __expf(e3);
    ((float4*)P)[d * VV + v] = p;
    return;
  }
  // x-transpose: xT[n*16+g] = x[g*NN+n]
  const int i = (blockIdx.x - NSCAT - VV) * 256 + threadIdx.x;
  if (i < GG * NN) {
    const int n = i >> 4, g = i & 15;
    xT[i] = x[g * NN + n];
  }
}

// ---------------------------------------------------------------------------
// Main kernel: one block per node, all 16 graphs (g = tid>>4), 16 lanes per
// graph, 8 channels per lane. csr row prefetched by the wave's 64 lanes and
// broadcast per edge via __shfl (readlane) -> 2-deep gather chain
// (xT -> P/T16). T16 row reads are 256 B coalesced per graph group; the
// denominator accumulates per-lane (no reductions, no LDS, no syncs).
// ---------------------------------------------------------------------------
__global__ __launch_bounds__(256)
void k_gat(const int* __restrict__ xT, const int* __restrict__ cursor,
           const int* __restrict__ csr, const __half* __restrict__ T16,
           const float* __restrict__ P, const float* __restrict__ bias,
           float* __restrict__ out) {
  const int tid  = threadIdx.x;
  const int n    = blockIdx.x;                // node
  const int g    = tid >> 4;                  // graph 0..15
  const int sl   = tid & 15;                  // sub-lane within graph group
  const int head = sl >> 2;                   // my 8 channels' head
  const int lane = tid & 63;

  const int base = n * CAP;
  const int deg  = min(cursor[n], CAP);       // includes self loop (slot 0)
  const int xd   = xT[n * 16 + g];
  const float* __restrict__ Pg = P + ((size_t)xd << 10) + head;  // index by xv*4

  const int my_csr = csr[base + lane];        // coalesced prefetch of slots 0..63

  float4 a_lo = make_float4(0.f, 0.f, 0.f, 0.f);
  float4 a_hi = make_float4(0.f, 0.f, 0.f, 0.f);
  float dsum = 0.f;

  const int d0 = min(deg, 64);
#pragma unroll 2
  for (int j = 0; j < d0; ++j) {
    const int srcn = __shfl(my_csr, j);       // readlane: csr[base+j]
    const int xv   = xT[(srcn << 4) + g];     // broadcast within 16-lane group
    const float p  = Pg[xv << 2];             // broadcast within 4-lane head group
    union { uint4 u; __half2 h2[4]; } tt;
    tt.u = *(const uint4*)&T16[((size_t)xv << 7) + sl * 8];  // 256 B/group coalesced
    const float2 f0 = __half22float2(tt.h2[0]);
    const float2 f1 = __half22float2(tt.h2[1]);
    const float2 f2 = __half22float2(tt.h2[2]);
    const float2 f3 = __half22float2(tt.h2[3]);
    a_lo.x += p * f0.x; a_lo.y += p * f0.y; a_lo.z += p * f1.x; a_lo.w += p * f1.y;
    a_hi.x += p * f2.x; a_hi.y += p * f2.y; a_hi.z += p * f3.x; a_hi.w += p * f3.y;
    dsum += p;
  }
  for (int j = 64; j < deg; ++j) {            // rare tail (deg>64 never seen; safe)
    const int srcn = csr[base + j];
    const int xv   = xT[(srcn << 4) + g];
    const float p  = Pg[xv << 2];
    union { uint4 u; __half2 h2[4]; } tt;
    tt.u = *(const uint4*)&T16[((size_t)xv << 7) + sl * 8];
    const float2 f0 = __half22float2(tt.h2[0]);
    const float2 f1 = __half22float2(tt.h2[1]);
    const float2 f2 = __half22float2(tt.h2[2]);
    const float2 f3 = __half22float2(tt.h2[3]);
    a_lo.x += p * f0.x; a_lo.y += p * f0.y; a_lo.z += p * f1.x; a_lo.w += p * f1.y;
    a_hi.x += p * f2.x; a_hi.y += p * f2.y; a_hi.z += p * f3.x; a_hi.w += p * f3.y;
    dsum += p;
  }

  const float r = 1.f / dsum;
  const float4 b_lo = ((const float4*)bias)[sl * 2];
  const float4 b_hi = ((const float4*)bias)[sl * 2 + 1];
  float4 o0, o1;
  o0.x = a_lo.x * r + b_lo.x; o0.y = a_lo.y * r + b_lo.y;
  o0.z = a_lo.z * r + b_lo.z; o0.w = a_lo.w * r + b_lo.w;
  o1.x = a_hi.x * r + b_hi.x; o1.y = a_hi.y * r + b_hi.y;
  o1.z = a_hi.z * r + b_hi.z; o1.w = a_hi.w * r + b_hi.w;
  float* op = out + ((size_t)(g * NN + n)) * HC + sl * 8;
  *(float4*)op = o0;
  *(float4*)(op + 4) = o1;
}

// ---------------------------------------------------------------------------
extern "C" void kernel_launch(void* const* d_in, const int* in_sizes, int n_in,
                              void* d_out, int out_size, void* d_ws, size_t ws_size,
                              hipStream_t stream) {
  const int*   x       = (const int*)d_in[0];      // [G,N]
  const int*   adj     = (const int*)d_in[1];      // [2,E]
  const float* emb     = (const float*)d_in[2];    // [V,F]
  const float* W       = (const float*)d_in[3];    // [F,HC]
  const float* att_src = (const float*)d_in[4];    // [H,C]
  const float* att_dst = (const float*)d_in[5];    // [H,C]
  const float* bias    = (const float*)d_in[6];    // [HC]
  float*       out     = (float*)d_out;

  const int* adj_src = adj;
  const int* adj_dst = adj + EE;

  // workspace carve-up (region sizes multiples of 16 B)
  char* wp = (char*)d_ws;
  __half* T16 = (__half*)wp; wp += (size_t)VV * HC * 2;      // 64 KB
  float* as_t = (float*)wp;  wp += (size_t)VV * HH * 4;      // 4 KB
  float* ad_t = (float*)wp;  wp += (size_t)VV * HH * 4;      // 4 KB
  int* cursor = (int*)wp;    wp += (size_t)NN * 4;           // 20000 B
  int* csr    = (int*)wp;    wp += (size_t)NN * CAP * 4;     // 1.92 MB
  float* P    = (float*)wp;  wp += (size_t)VV * VV * HH * 4; // 1 MB
  int* xT     = (int*)wp;    wp += (size_t)GG * NN * 4;      // 320 KB

  const int initblk = (NN + 127) / 128;                      // 40
  k_tables<<<VV + initblk, 128, 0, stream>>>(emb, W, att_src, att_dst,
                                             T16, as_t, ad_t, cursor, csr);
  k_scatter_p<<<NSCAT + VV + NXT, 256, 0, stream>>>(adj_src, adj_dst, cursor, csr,
                                                    as_t, ad_t, P, x, xT);
  k_gat<<<NN, 256, 0, stream>>>(xT, cursor, csr, T16, P, bias, out);
}